// Round 4
// baseline (879.177 us; speedup 1.0000x reference)
//
#include <hip/hip_runtime.h>
#include <math.h>

#define S_DIM 4
#define F_DIM 1128
#define T_DIM 1000
#define D_DIM 13
#define SF_DIM (S_DIM * F_DIM)      // 4512
#define NSUM 104                     // 13 mean + 91 packed upper-tri m2

// packed index helpers
__device__ __forceinline__ constexpr int LIdx(int r, int c) { return r * (r + 1) / 2 + c; }           // lower, r>=c
__device__ __forceinline__ constexpr int UIdx(int i, int j) { return i * 13 - i * (i - 1) / 2 + (j - i); } // upper, i<=j

// ---------------------------------------------------------------------------
// Kernel 1: per-(s,f,tensor) sums: mean-sum[13] and m2-sum[91] over all T frames.
// One FULL wave (64 lanes) per task, 9024 waves total, plus a depth-1 software
// prefetch pipeline (cur/nxt float4[13] double buffer): every ~832-cycle
// compute burst has the next 13x16B-per-lane load burst (13.3 KB/wave) in
// flight. The compiler's dependence-driven waitcnt gives counted waits
// (accum(cur) only drains to vmcnt(13), leaving nxt's loads outstanding).
// __launch_bounds__(64, 2): ~225 live VGPRs (acc[104] + 2x 52-float staging);
// asking for more waves/EU would cap VGPRs (gfx950 pool 512/SIMD: 4/EU => 128,
// 8/EU => 64) and force acc[] to spill to scratch. 2/EU = 8 waves/CU resident,
// ~106 KB in flight per CU >> the ~9 KB needed to cover ~900-cyc HBM latency
// at the per-CU HBM share (~10 B/cyc).
// ---------------------------------------------------------------------------
__device__ __forceinline__ void load_sf(const float* __restrict__ v, int k, float4* dst) {
    const float4* p4 = (const float4*)(v + (size_t)k * 52);
#pragma unroll
    for (int i = 0; i < 13; ++i) dst[i] = p4[i];
}

__device__ __forceinline__ void accum_sf(const float4* src, float* acc) {
    const float* x = (const float*)src;
#pragma unroll
    for (int t = 0; t < 4; ++t) {
        int kk = 13;
#pragma unroll
        for (int i = 0; i < 13; ++i) {
            float xi = x[t * 13 + i];
            acc[i] += xi;
#pragma unroll
            for (int j = i; j < 13; ++j) {
                acc[kk] += xi * x[t * 13 + j];
                ++kk;
            }
        }
    }
}

__global__ __launch_bounds__(64, 2) void moments_kernel(const float* __restrict__ pv,
                                                        const float* __restrict__ qv,
                                                        float* __restrict__ sums) {
    const int l = threadIdx.x;           // 0..63
    const int which = blockIdx.y;        // 0 = p, 1 = q
    const int sf = blockIdx.x;           // 0..4511

    const float* __restrict__ v = (which == 0 ? pv : qv) + (size_t)sf * (T_DIM * D_DIM);

    float acc[NSUM];
#pragma unroll
    for (int i = 0; i < NSUM; ++i) acc[i] = 0.0f;

    float4 cur[13], nxt[13];
    const bool tail = (l < 250 - 192);   // l < 58: 250 superframes total

    // pipeline: [load c0][load n1] C(c0) [load c2] C(n1) [load n3] C(c2) C(n3)
    load_sf(v, l, cur);
    load_sf(v, l + 64, nxt);
    accum_sf(cur, acc);
    load_sf(v, l + 128, cur);
    accum_sf(nxt, acc);
    if (tail) load_sf(v, l + 192, nxt);
    accum_sf(cur, acc);
    if (tail) accum_sf(nxt, acc);

    // butterfly reduce across the full 64-lane wave
#pragma unroll
    for (int i = 0; i < NSUM; ++i) {
        acc[i] += __shfl_xor(acc[i], 1);
        acc[i] += __shfl_xor(acc[i], 2);
        acc[i] += __shfl_xor(acc[i], 4);
        acc[i] += __shfl_xor(acc[i], 8);
        acc[i] += __shfl_xor(acc[i], 16);
        acc[i] += __shfl_xor(acc[i], 32);
    }

    if (l == 0) {
        float* o = sums + ((size_t)which * SF_DIM + sf) * NSUM;
#pragma unroll
        for (int i = 0; i < NSUM; ++i) o[i] = acc[i];
    }
}

// ---------------------------------------------------------------------------
// Kernel 2: per-(s,f) symmetric KL in fp64 (packed Cholesky), -> feats
// ---------------------------------------------------------------------------
__device__ __forceinline__ void chol13(double* A) {
#pragma unroll
    for (int c = 0; c < 13; ++c) {
        double dg = A[LIdx(c, c)];
#pragma unroll
        for (int t = 0; t < c; ++t) { double v = A[LIdx(c, t)]; dg -= v * v; }
        dg = sqrt(dg);
        A[LIdx(c, c)] = dg;
        double inv = 1.0 / dg;
#pragma unroll
        for (int r = c + 1; r < 13; ++r) {
            double s = A[LIdx(r, c)];
#pragma unroll
            for (int t = 0; t < c; ++t) s -= A[LIdx(r, t)] * A[LIdx(c, t)];
            A[LIdx(r, c)] = s * inv;
        }
    }
}

__device__ __forceinline__ double trsolve_fro2(const double* Lden, const double* Lnum) {
    // || Lden^{-1} Lnum ||_F^2  (both lower-triangular packed; result is lower-tri)
    double tr = 0.0;
#pragma unroll
    for (int j = 0; j < 13; ++j) {
        double x[13];
#pragma unroll
        for (int r = j; r < 13; ++r) {
            double s = Lnum[LIdx(r, j)];
#pragma unroll
            for (int t = j; t < r; ++t) s -= Lden[LIdx(r, t)] * x[t];
            x[r] = s / Lden[LIdx(r, r)];
            tr += x[r] * x[r];
        }
    }
    return tr;
}

__device__ __forceinline__ double quadsolve(const double* L, const double* dvec) {
    double x[13];
    double q = 0.0;
#pragma unroll
    for (int r = 0; r < 13; ++r) {
        double s = dvec[r];
#pragma unroll
        for (int t = 0; t < r; ++t) s -= L[LIdx(r, t)] * x[t];
        x[r] = s / L[LIdx(r, r)];
        q += x[r] * x[r];
    }
    return q;
}

__global__ __launch_bounds__(64, 1) void kl_kernel(const float* __restrict__ sums,
                                                   const float* __restrict__ plen,
                                                   const float* __restrict__ qlen,
                                                   const float* __restrict__ mask,
                                                   float* __restrict__ feats) {
    const int sf = blockIdx.x * 64 + threadIdx.x;
    if (sf >= SF_DIM) return;
    const float* ps = sums + (size_t)sf * NSUM;
    const float* qs = sums + (size_t)(SF_DIM + sf) * NSUM;
    const double lp = (double)plen[sf];
    const double lq = (double)qlen[sf];

    double mp[13], mq[13];
#pragma unroll
    for (int i = 0; i < 13; ++i) {
        mp[i] = (double)ps[i] / lp;
        mq[i] = (double)qs[i] / lq;
    }

    double Lp[91], Lq[91];
#pragma unroll
    for (int r = 0; r < 13; ++r) {
#pragma unroll
        for (int c = 0; c <= r; ++c) {
            double ep = (r == c) ? 1e-3 : 0.0;
            Lp[LIdx(r, c)] = (double)ps[13 + UIdx(c, r)] / lp - mp[c] * mp[r] + ep;
            Lq[LIdx(r, c)] = (double)qs[13 + UIdx(c, r)] / lq - mq[c] * mq[r] + ep;
        }
    }

    double dvec[13];
#pragma unroll
    for (int i = 0; i < 13; ++i) dvec[i] = mp[i] - mq[i];

    chol13(Lp);
    chol13(Lq);

    double tr = trsolve_fro2(Lq, Lp) + trsolve_fro2(Lp, Lq);
    double quad = quadsolve(Lq, dvec) + quadsolve(Lp, dvec);
    double kl = 0.25 * (tr + quad - 2.0 * 13.0);

    double ft = log(kl + 1e-5);
    double m = (double)mask[sf];
    feats[sf] = (float)((ft + 1.0) * m - 1.0);
}

// ---------------------------------------------------------------------------
// MLP: split-K partial GEMV per layer. Each block owns an i-chunk; staging
// reduces the PREVIOUS layer's partials (+bias+ReLU), or applies BatchNorm to
// feats for layer 1. Staging is parallelized over (idx, s) pairs: 4*clen
// threads each sum prev_ns partials (instead of clen threads doing 4*prev_ns
// serial loads). Compute: each lane owns 4 output columns (float4 W loads).
// ---------------------------------------------------------------------------
__global__ __launch_bounds__(256) void layer_partial(const float* __restrict__ W,
                                                     const int in_dim, const int out_dim,
                                                     const int chunk,
                                                     const float* __restrict__ prev_part,
                                                     const int prev_ns,
                                                     const float* __restrict__ prev_bias,
                                                     const float* __restrict__ feats,
                                                     const float* __restrict__ gamma,
                                                     const float* __restrict__ beta,
                                                     float* __restrict__ out_part) {
    __shared__ float hlds[4][48];
    const int p = blockIdx.x;
    const int i0 = p * chunk;
    const int clen = min(chunk, in_dim - i0);
    const int tid = threadIdx.x;

    if (feats != nullptr) {
        // layer 1: BatchNorm(feats) staged into LDS
        if (tid < clen) {
            const int f = i0 + tid;
            float v0 = feats[f];
            float v1 = feats[F_DIM + f];
            float v2 = feats[2 * F_DIM + f];
            float v3 = feats[3 * F_DIM + f];
            float mu = 0.25f * (v0 + v1 + v2 + v3);
            float d0 = v0 - mu, d1 = v1 - mu, d2 = v2 - mu, d3 = v3 - mu;
            float var = 0.25f * (d0 * d0 + d1 * d1 + d2 * d2 + d3 * d3);
            float inv = 1.0f / sqrtf(var + 1e-5f);
            float ga = gamma[f], be = beta[f];
            hlds[0][tid] = d0 * inv * ga + be;
            hlds[1][tid] = d1 * inv * ga + be;
            hlds[2][tid] = d2 * inv * ga + be;
            hlds[3][tid] = d3 * inv * ga + be;
        }
    } else {
        // middle layers: reduce prev partials + bias + relu.
        // tid -> (idx = tid>>2, s = tid&3); 4*clen <= 192 active threads,
        // each sums prev_ns values (4x shorter critical path than clen
        // threads x 4*prev_ns serial loads).
        const int idx = tid >> 2;
        const int s = tid & 3;
        if (idx < clen) {
            const int i = i0 + idx;
            float a = prev_bias[i];
            for (int pp = 0; pp < prev_ns; ++pp) {
                a += prev_part[((size_t)pp * 4 + s) * in_dim + i];
            }
            hlds[s][idx] = fmaxf(a, 0.0f);
        }
    }
    __syncthreads();

    const int j4 = tid * 4;
    if (j4 < out_dim) {
        float acc[4][4] = {{0.f, 0.f, 0.f, 0.f}, {0.f, 0.f, 0.f, 0.f},
                           {0.f, 0.f, 0.f, 0.f}, {0.f, 0.f, 0.f, 0.f}};
        for (int idx = 0; idx < clen; ++idx) {
            float4 w = *(const float4*)(W + (size_t)(i0 + idx) * out_dim + j4);
#pragma unroll
            for (int s = 0; s < 4; ++s) {
                float h = hlds[s][idx];
                acc[s][0] += h * w.x;
                acc[s][1] += h * w.y;
                acc[s][2] += h * w.z;
                acc[s][3] += h * w.w;
            }
        }
#pragma unroll
        for (int s = 0; s < 4; ++s) {
            float4 o = make_float4(acc[s][0], acc[s][1], acc[s][2], acc[s][3]);
            *(float4*)(out_part + ((size_t)p * 4 + s) * out_dim + j4) = o;
        }
    }
}

// Layer 7 (1000 -> 1): per-block partial dot over an i-chunk.
__global__ __launch_bounds__(256) void layer7_partial(const float* __restrict__ W7,
                                                      const float* __restrict__ part6,
                                                      const float* __restrict__ b6,
                                                      float* __restrict__ part7,
                                                      const int in_dim, const int chunk,
                                                      const int prev_ns) {
    __shared__ float hl[4][32];
    __shared__ float wl[32];
    const int p = blockIdx.x;
    const int i0 = p * chunk;
    const int clen = min(chunk, in_dim - i0);
    const int tid = threadIdx.x;

    // parallel staging: tid -> (idx, s)
    {
        const int idx = tid >> 2;
        const int s = tid & 3;
        if (idx < clen) {
            const int i = i0 + idx;
            float a = b6[i];
            for (int pp = 0; pp < prev_ns; ++pp) {
                a += part6[((size_t)pp * 4 + s) * in_dim + i];
            }
            hl[s][idx] = fmaxf(a, 0.0f);
            if (s == 0) wl[idx] = W7[i];
        }
    }
    __syncthreads();

    if (tid < 4) {
        float acc = 0.0f;
        for (int idx = 0; idx < clen; ++idx) acc += hl[tid][idx] * wl[idx];
        part7[p * 4 + tid] = acc;
    }
}

__global__ void final_kernel(const float* __restrict__ part7,
                             const float* __restrict__ b7,
                             float* __restrict__ out, const int ns) {
    const int s = threadIdx.x;
    if (s < 4) {
        float acc = b7[0];
        for (int p = 0; p < ns; ++p) acc += part7[p * 4 + s];
        out[s] = acc;
    }
}

// ---------------------------------------------------------------------------
extern "C" void kernel_launch(void* const* d_in, const int* in_sizes, int n_in,
                              void* d_out, int out_size, void* d_ws, size_t ws_size,
                              hipStream_t stream) {
    const float* pv    = (const float*)d_in[0];
    const float* qv    = (const float*)d_in[1];
    const float* plen  = (const float*)d_in[2];
    const float* qlen  = (const float*)d_in[3];
    const float* mask  = (const float*)d_in[4];
    const float* gamma = (const float*)d_in[5];
    const float* beta  = (const float*)d_in[6];
    const float* W[7];
    const float* b[7];
    for (int i = 0; i < 7; ++i) {
        W[i] = (const float*)d_in[7 + 2 * i];
        b[i] = (const float*)d_in[8 + 2 * i];
    }

    float* ws = (float*)d_ws;
    float* sums  = ws;                                  // 2*4512*104 = 938496 floats
    float* feats = ws + 938496;                         // 4512 floats
    float* partA = ws + 943008;                         // 32*4*1000 = 128000 floats (16B-aligned)
    float* partB = partA + 128000;                      // 128000 floats
    float* part7 = partB + 128000;                      // 128 floats
    float* out = (float*)d_out;

    // 1) moments: one wave per (sf, tensor) task, 9024 waves
    moments_kernel<<<dim3(4512, 2), 64, 0, stream>>>(pv, qv, sums);
    // 2) symmetric KL -> feats
    kl_kernel<<<dim3(71), 64, 0, stream>>>(sums, plen, qlen, mask, feats);
    // 3) MLP. L1 fuses BatchNorm; each layer fuses prev partial-reduce+bias+relu.
    layer_partial<<<32, 256, 0, stream>>>(W[0], 1128, 1000, 36, nullptr, 0, nullptr,
                                          feats, gamma, beta, partA);
    layer_partial<<<32, 256, 0, stream>>>(W[1], 1000, 1000, 32, partA, 32, b[0],
                                          nullptr, nullptr, nullptr, partB);
    layer_partial<<<32, 256, 0, stream>>>(W[2], 1000, 1000, 32, partB, 32, b[1],
                                          nullptr, nullptr, nullptr, partA);
    layer_partial<<<32, 256, 0, stream>>>(W[3], 1000, 1000, 32, partA, 32, b[2],
                                          nullptr, nullptr, nullptr, partB);
    layer_partial<<<32, 256, 0, stream>>>(W[4], 1000, 1000, 32, partB, 32, b[3],
                                          nullptr, nullptr, nullptr, partA);
    layer_partial<<<32, 256, 0, stream>>>(W[5], 1000, 1000, 32, partA, 32, b[4],
                                          nullptr, nullptr, nullptr, partB);
    layer7_partial<<<32, 256, 0, stream>>>(W[6], partB, b[5], part7, 1000, 32, 32);
    final_kernel<<<1, 64, 0, stream>>>(part7, b[6], out, 32);
}

// Round 9
// 644.805 us; speedup vs baseline: 1.3635x; 1.3635x over previous
//
#include <hip/hip_runtime.h>
#include <math.h>

#define S_DIM 4
#define F_DIM 1128
#define T_DIM 1000
#define D_DIM 13
#define SF_DIM (S_DIM * F_DIM)      // 4512
#define NSUM 104                     // 13 mean + 91 packed upper-tri m2

// packed index helpers
__device__ __forceinline__ constexpr int LIdx(int r, int c) { return r * (r + 1) / 2 + c; }           // lower, r>=c
__device__ __forceinline__ constexpr int UIdx(int i, int j) { return i * 13 - i * (i - 1) / 2 + (j - i); } // upper, i<=j

// ---------------------------------------------------------------------------
// Kernel 1: per-(s,f,tensor) sums: mean-sum[13] + m2-sum[91] over T frames.
//
// Round-4 counters (hardware fact): VGPR_Count=128 with ~225 live values =>
// scratch spill (WRITE_SIZE 286 MB vs 3.75 MB real output), 282 us, VALUBusy
// 8.5%. Fix: PAIR-SPLIT so peak register demand ~114 < 128 (no spill at the
// allocator's preferred budget, 4 waves/EU occupancy):
//   - team = lane pair (2k, 2k+1); each lane loads one frame-pair (2 frames,
//     26 floats, 8B-aligned float2 loads: pair m starts at byte 104*m).
//   - teammate's 26 values arrive via __shfl_xor(.,1), wave-uniform.
//   - even lanes accumulate sums kk=0..51, odd lanes kk=52..103, each over
//     the team's 4 frames. Total FMA issue equals the unsplit version.
//   - butterfly reduce with parity-preserving masks {2,4,8,16,32}; lane 0
//     writes sums[0:52), lane 1 writes sums[52:104) => layout identical,
//     kl_kernel unchanged.
//   - #pragma unroll 1 on the 8-round loop: prevents full unroll from
//     inflating live ranges past 128 (the exact round-4 failure mode).
// Teams always share validity: pairs 500..511 (zero-filled) are whole teams.
// ---------------------------------------------------------------------------
template<int LO, int HI>
__device__ __forceinline__ void accum_range(const float* __restrict__ x,
                                            float* __restrict__ acc) {
    int kk = 0;
#pragma unroll
    for (int i = 0; i < 13; ++i) {          // means: kk = 0..12
        if (kk >= LO && kk < HI) acc[kk - LO] += x[i];
        ++kk;
    }
#pragma unroll
    for (int i = 0; i < 13; ++i) {          // m2 upper-tri: kk = 13..103
#pragma unroll
        for (int j = i; j < 13; ++j) {
            if (kk >= LO && kk < HI) acc[kk - LO] += x[i] * x[j];
            ++kk;
        }
    }
}

__global__ __launch_bounds__(64) void moments_kernel(const float* __restrict__ pv,
                                                     const float* __restrict__ qv,
                                                     float* __restrict__ sums) {
    const int l = threadIdx.x;           // 0..63
    const int which = blockIdx.y;        // 0 = p, 1 = q
    const int sf = blockIdx.x;           // 0..4511

    const float* __restrict__ v = (which == 0 ? pv : qv) + (size_t)sf * (T_DIM * D_DIM);

    float acc[52];
#pragma unroll
    for (int i = 0; i < 52; ++i) acc[i] = 0.0f;

    const bool odd = (l & 1);

    // 500 frame-pairs; lane l handles pair m = l, l+64, ... (8 rounds, last partial)
#pragma unroll 1
    for (int it = 0; it < 8; ++it) {
        const int m = l + 64 * it;       // frame-pair index
        float x[26];
        if (m < 500) {
            const float2* p2 = (const float2*)(v + (size_t)m * 26);  // 104*m bytes, 8B-aligned
#pragma unroll
            for (int i = 0; i < 13; ++i) {
                float2 t = p2[i];
                x[2 * i]     = t.x;
                x[2 * i + 1] = t.y;
            }
        } else {
#pragma unroll
            for (int i = 0; i < 26; ++i) x[i] = 0.0f;   // zero frames contribute nothing
        }

        // teammate's two frames (wave-uniform shuffles; never inside divergence)
        float y0[13], y1[13];
#pragma unroll
        for (int i = 0; i < 13; ++i) y0[i] = __shfl_xor(x[i], 1);
#pragma unroll
        for (int i = 0; i < 13; ++i) y1[i] = __shfl_xor(x[13 + i], 1);

        if (!odd) {
            accum_range<0, 52>(x, acc);        // own frame 2m
            accum_range<0, 52>(x + 13, acc);   // own frame 2m+1
            accum_range<0, 52>(y0, acc);       // teammate frame
            accum_range<0, 52>(y1, acc);       // teammate frame
        } else {
            accum_range<52, 104>(x, acc);
            accum_range<52, 104>(x + 13, acc);
            accum_range<52, 104>(y0, acc);
            accum_range<52, 104>(y1, acc);
        }
    }

    // butterfly reduce across same-parity lanes (masks keep parity classes)
#pragma unroll
    for (int i = 0; i < 52; ++i) {
        acc[i] += __shfl_xor(acc[i], 2);
        acc[i] += __shfl_xor(acc[i], 4);
        acc[i] += __shfl_xor(acc[i], 8);
        acc[i] += __shfl_xor(acc[i], 16);
        acc[i] += __shfl_xor(acc[i], 32);
    }

    if (l < 2) {
        float* o = sums + ((size_t)which * SF_DIM + sf) * NSUM + (size_t)l * 52;
#pragma unroll
        for (int i = 0; i < 52; ++i) o[i] = acc[i];
    }
}

// ---------------------------------------------------------------------------
// Kernel 2: per-(s,f) symmetric KL in fp64 (packed Cholesky), -> feats
// ---------------------------------------------------------------------------
__device__ __forceinline__ void chol13(double* A) {
#pragma unroll
    for (int c = 0; c < 13; ++c) {
        double dg = A[LIdx(c, c)];
#pragma unroll
        for (int t = 0; t < c; ++t) { double v = A[LIdx(c, t)]; dg -= v * v; }
        dg = sqrt(dg);
        A[LIdx(c, c)] = dg;
        double inv = 1.0 / dg;
#pragma unroll
        for (int r = c + 1; r < 13; ++r) {
            double s = A[LIdx(r, c)];
#pragma unroll
            for (int t = 0; t < c; ++t) s -= A[LIdx(r, t)] * A[LIdx(c, t)];
            A[LIdx(r, c)] = s * inv;
        }
    }
}

__device__ __forceinline__ double trsolve_fro2(const double* Lden, const double* Lnum) {
    // || Lden^{-1} Lnum ||_F^2  (both lower-triangular packed; result is lower-tri)
    double tr = 0.0;
#pragma unroll
    for (int j = 0; j < 13; ++j) {
        double x[13];
#pragma unroll
        for (int r = j; r < 13; ++r) {
            double s = Lnum[LIdx(r, j)];
#pragma unroll
            for (int t = j; t < r; ++t) s -= Lden[LIdx(r, t)] * x[t];
            x[r] = s / Lden[LIdx(r, r)];
            tr += x[r] * x[r];
        }
    }
    return tr;
}

__device__ __forceinline__ double quadsolve(const double* L, const double* dvec) {
    double x[13];
    double q = 0.0;
#pragma unroll
    for (int r = 0; r < 13; ++r) {
        double s = dvec[r];
#pragma unroll
        for (int t = 0; t < r; ++t) s -= L[LIdx(r, t)] * x[t];
        x[r] = s / L[LIdx(r, r)];
        q += x[r] * x[r];
    }
    return q;
}

__global__ __launch_bounds__(64, 1) void kl_kernel(const float* __restrict__ sums,
                                                   const float* __restrict__ plen,
                                                   const float* __restrict__ qlen,
                                                   const float* __restrict__ mask,
                                                   float* __restrict__ feats) {
    const int sf = blockIdx.x * 64 + threadIdx.x;
    if (sf >= SF_DIM) return;
    const float* ps = sums + (size_t)sf * NSUM;
    const float* qs = sums + (size_t)(SF_DIM + sf) * NSUM;
    const double lp = (double)plen[sf];
    const double lq = (double)qlen[sf];

    double mp[13], mq[13];
#pragma unroll
    for (int i = 0; i < 13; ++i) {
        mp[i] = (double)ps[i] / lp;
        mq[i] = (double)qs[i] / lq;
    }

    double Lp[91], Lq[91];
#pragma unroll
    for (int r = 0; r < 13; ++r) {
#pragma unroll
        for (int c = 0; c <= r; ++c) {
            double ep = (r == c) ? 1e-3 : 0.0;
            Lp[LIdx(r, c)] = (double)ps[13 + UIdx(c, r)] / lp - mp[c] * mp[r] + ep;
            Lq[LIdx(r, c)] = (double)qs[13 + UIdx(c, r)] / lq - mq[c] * mq[r] + ep;
        }
    }

    double dvec[13];
#pragma unroll
    for (int i = 0; i < 13; ++i) dvec[i] = mp[i] - mq[i];

    chol13(Lp);
    chol13(Lq);

    double tr = trsolve_fro2(Lq, Lp) + trsolve_fro2(Lp, Lq);
    double quad = quadsolve(Lq, dvec) + quadsolve(Lp, dvec);
    double kl = 0.25 * (tr + quad - 2.0 * 13.0);

    double ft = log(kl + 1e-5);
    double m = (double)mask[sf];
    feats[sf] = (float)((ft + 1.0) * m - 1.0);
}

// ---------------------------------------------------------------------------
// MLP: split-K partial GEMV per layer. Each block owns an i-chunk; staging
// reduces the PREVIOUS layer's partials (+bias+ReLU), or applies BatchNorm to
// feats for layer 1. Staging is parallelized over (idx, s) pairs: 4*clen
// threads each sum prev_ns partials. Compute: each lane owns 4 output
// columns (float4 W loads).
// ---------------------------------------------------------------------------
__global__ __launch_bounds__(256) void layer_partial(const float* __restrict__ W,
                                                     const int in_dim, const int out_dim,
                                                     const int chunk,
                                                     const float* __restrict__ prev_part,
                                                     const int prev_ns,
                                                     const float* __restrict__ prev_bias,
                                                     const float* __restrict__ feats,
                                                     const float* __restrict__ gamma,
                                                     const float* __restrict__ beta,
                                                     float* __restrict__ out_part) {
    __shared__ float hlds[4][48];
    const int p = blockIdx.x;
    const int i0 = p * chunk;
    const int clen = min(chunk, in_dim - i0);
    const int tid = threadIdx.x;

    if (feats != nullptr) {
        // layer 1: BatchNorm(feats) staged into LDS
        if (tid < clen) {
            const int f = i0 + tid;
            float v0 = feats[f];
            float v1 = feats[F_DIM + f];
            float v2 = feats[2 * F_DIM + f];
            float v3 = feats[3 * F_DIM + f];
            float mu = 0.25f * (v0 + v1 + v2 + v3);
            float d0 = v0 - mu, d1 = v1 - mu, d2 = v2 - mu, d3 = v3 - mu;
            float var = 0.25f * (d0 * d0 + d1 * d1 + d2 * d2 + d3 * d3);
            float inv = 1.0f / sqrtf(var + 1e-5f);
            float ga = gamma[f], be = beta[f];
            hlds[0][tid] = d0 * inv * ga + be;
            hlds[1][tid] = d1 * inv * ga + be;
            hlds[2][tid] = d2 * inv * ga + be;
            hlds[3][tid] = d3 * inv * ga + be;
        }
    } else {
        // middle layers: reduce prev partials + bias + relu.
        // tid -> (idx = tid>>2, s = tid&3); 4*clen <= 192 active threads,
        // each sums prev_ns values.
        const int idx = tid >> 2;
        const int s = tid & 3;
        if (idx < clen) {
            const int i = i0 + idx;
            float a = prev_bias[i];
            for (int pp = 0; pp < prev_ns; ++pp) {
                a += prev_part[((size_t)pp * 4 + s) * in_dim + i];
            }
            hlds[s][idx] = fmaxf(a, 0.0f);
        }
    }
    __syncthreads();

    const int j4 = tid * 4;
    if (j4 < out_dim) {
        float acc[4][4] = {{0.f, 0.f, 0.f, 0.f}, {0.f, 0.f, 0.f, 0.f},
                           {0.f, 0.f, 0.f, 0.f}, {0.f, 0.f, 0.f, 0.f}};
        for (int idx = 0; idx < clen; ++idx) {
            float4 w = *(const float4*)(W + (size_t)(i0 + idx) * out_dim + j4);
#pragma unroll
            for (int s = 0; s < 4; ++s) {
                float h = hlds[s][idx];
                acc[s][0] += h * w.x;
                acc[s][1] += h * w.y;
                acc[s][2] += h * w.z;
                acc[s][3] += h * w.w;
            }
        }
#pragma unroll
        for (int s = 0; s < 4; ++s) {
            float4 o = make_float4(acc[s][0], acc[s][1], acc[s][2], acc[s][3]);
            *(float4*)(out_part + ((size_t)p * 4 + s) * out_dim + j4) = o;
        }
    }
}

// Layer 7 (1000 -> 1): per-block partial dot over an i-chunk.
__global__ __launch_bounds__(256) void layer7_partial(const float* __restrict__ W7,
                                                      const float* __restrict__ part6,
                                                      const float* __restrict__ b6,
                                                      float* __restrict__ part7,
                                                      const int in_dim, const int chunk,
                                                      const int prev_ns) {
    __shared__ float hl[4][32];
    __shared__ float wl[32];
    const int p = blockIdx.x;
    const int i0 = p * chunk;
    const int clen = min(chunk, in_dim - i0);
    const int tid = threadIdx.x;

    // parallel staging: tid -> (idx, s)
    {
        const int idx = tid >> 2;
        const int s = tid & 3;
        if (idx < clen) {
            const int i = i0 + idx;
            float a = b6[i];
            for (int pp = 0; pp < prev_ns; ++pp) {
                a += part6[((size_t)pp * 4 + s) * in_dim + i];
            }
            hl[s][idx] = fmaxf(a, 0.0f);
            if (s == 0) wl[idx] = W7[i];
        }
    }
    __syncthreads();

    if (tid < 4) {
        float acc = 0.0f;
        for (int idx = 0; idx < clen; ++idx) acc += hl[tid][idx] * wl[idx];
        part7[p * 4 + tid] = acc;
    }
}

__global__ void final_kernel(const float* __restrict__ part7,
                             const float* __restrict__ b7,
                             float* __restrict__ out, const int ns) {
    const int s = threadIdx.x;
    if (s < 4) {
        float acc = b7[0];
        for (int p = 0; p < ns; ++p) acc += part7[p * 4 + s];
        out[s] = acc;
    }
}

// ---------------------------------------------------------------------------
extern "C" void kernel_launch(void* const* d_in, const int* in_sizes, int n_in,
                              void* d_out, int out_size, void* d_ws, size_t ws_size,
                              hipStream_t stream) {
    const float* pv    = (const float*)d_in[0];
    const float* qv    = (const float*)d_in[1];
    const float* plen  = (const float*)d_in[2];
    const float* qlen  = (const float*)d_in[3];
    const float* mask  = (const float*)d_in[4];
    const float* gamma = (const float*)d_in[5];
    const float* beta  = (const float*)d_in[6];
    const float* W[7];
    const float* b[7];
    for (int i = 0; i < 7; ++i) {
        W[i] = (const float*)d_in[7 + 2 * i];
        b[i] = (const float*)d_in[8 + 2 * i];
    }

    float* ws = (float*)d_ws;
    float* sums  = ws;                                  // 2*4512*104 = 938496 floats
    float* feats = ws + 938496;                         // 4512 floats
    float* partA = ws + 943008;                         // 32*4*1000 = 128000 floats (16B-aligned)
    float* partB = partA + 128000;                      // 128000 floats
    float* part7 = partB + 128000;                      // 128 floats
    float* out = (float*)d_out;

    // 1) moments: one wave per (sf, tensor) task, 9024 waves
    moments_kernel<<<dim3(4512, 2), 64, 0, stream>>>(pv, qv, sums);
    // 2) symmetric KL -> feats
    kl_kernel<<<dim3(71), 64, 0, stream>>>(sums, plen, qlen, mask, feats);
    // 3) MLP. L1 fuses BatchNorm; each layer fuses prev partial-reduce+bias+relu.
    layer_partial<<<32, 256, 0, stream>>>(W[0], 1128, 1000, 36, nullptr, 0, nullptr,
                                          feats, gamma, beta, partA);
    layer_partial<<<32, 256, 0, stream>>>(W[1], 1000, 1000, 32, partA, 32, b[0],
                                          nullptr, nullptr, nullptr, partB);
    layer_partial<<<32, 256, 0, stream>>>(W[2], 1000, 1000, 32, partB, 32, b[1],
                                          nullptr, nullptr, nullptr, partA);
    layer_partial<<<32, 256, 0, stream>>>(W[3], 1000, 1000, 32, partA, 32, b[2],
                                          nullptr, nullptr, nullptr, partB);
    layer_partial<<<32, 256, 0, stream>>>(W[4], 1000, 1000, 32, partB, 32, b[3],
                                          nullptr, nullptr, nullptr, partA);
    layer_partial<<<32, 256, 0, stream>>>(W[5], 1000, 1000, 32, partA, 32, b[4],
                                          nullptr, nullptr, nullptr, partB);
    layer7_partial<<<32, 256, 0, stream>>>(W[6], partB, b[5], part7, 1000, 32, 32);
    final_kernel<<<1, 64, 0, stream>>>(part7, b[6], out, 32);
}